// Round 9
// baseline (652.392 us; speedup 1.0000x reference)
//
#include <hip/hip_runtime.h>

#define D 32
#define NT 128
#define TR 64          // y/x rows staged per LDS tile
#define LOG2E 1.4426950408889634f

__device__ __forceinline__ void decode_pair(const void* comb, int B, int C,
                                            int pair, int flip, int& a, int& b) {
    const long long* c64 = (const long long*)comb;
    const int* c32 = (const int*)comb;
    bool is64 = true;
    for (int q = 0; q < C; ++q) {
        long long v = c64[q];
        if (v < 0 || v >= (long long)B) { is64 = false; break; }
    }
    if (is64) { a = (int)c64[2 * pair]; b = (int)c64[2 * pair + 1]; }
    else      { a = c32[2 * pair];      b = c32[2 * pair + 1]; }
    if (flip) { int t = a; a = b; b = t; }
}

// ---------------- K0: per-row squared norms, pre-scaled by log2(e) ----------------
__global__ __launch_bounds__(256)
void row_norms(const float* __restrict__ seq, float* __restrict__ norms, int nrows) {
    const int r = blockIdx.x * 256 + threadIdx.x;
    if (r >= nrows) return;
    const float* p = seq + (size_t)r * D;
    float s = 0.f;
    #pragma unroll
    for (int c = 0; c < 8; ++c) {
        float4 v = *(const float4*)(p + 4 * c);
        s = fmaf(v.x, v.x, fmaf(v.y, v.y, fmaf(v.z, v.z, fmaf(v.w, v.w, s))));
    }
    norms[r] = LOG2E * s;
}

// ---------------- K1: phase-A partial, LDS tiles + R=2 rows/lane + branch-free exp2 ----------------
// ws1 slot (33 fields, field-major): f=0: s, f=1..32: acc[d]
__global__ __launch_bounds__(NT)
void ccl_phaseA(const float* __restrict__ seq, const int* __restrict__ src_len,
                const void* __restrict__ comb, const float* __restrict__ norms,
                float* __restrict__ ws1, int T, int B, int C, int JS, int JC) {
    const int dir = blockIdx.x, pair = dir >> 1, flip = dir & 1;
    int a, b; decode_pair(comb, B, C, pair, flip, a, b);
    const int Lx = src_len[a] >> 2, Ly = src_len[b] >> 2;
    const int r0 = blockIdx.y * (2 * NT);
    if (r0 >= Lx) return;
    const int js = blockIdx.z;
    const int j0 = js * JC;
    if (j0 >= Ly) return;
    const int j1 = min(Ly, j0 + JC);
    const int tid = threadIdx.x;
    const int iA = r0 + tid;
    const int iB = iA + NT;
    const int icA = min(iA, Lx - 1);
    const int icB = min(iB, Lx - 1);

    const float* __restrict__ xbase = seq + (size_t)a * T * D;
    const float* __restrict__ ybase = seq + (size_t)b * T * D;
    const float* __restrict__ ny = norms + (size_t)b * T;

    float xA[D], xB[D];
    {
        const float k2 = 2.f * LOG2E;
        const float* ra = xbase + (size_t)icA * D;
        const float* rb = xbase + (size_t)icB * D;
        #pragma unroll
        for (int c = 0; c < 8; ++c) {
            float4 va = *(const float4*)(ra + 4 * c);
            float4 vb = *(const float4*)(rb + 4 * c);
            xA[4*c]=k2*va.x; xA[4*c+1]=k2*va.y; xA[4*c+2]=k2*va.z; xA[4*c+3]=k2*va.w;
            xB[4*c]=k2*vb.x; xB[4*c+1]=k2*vb.y; xB[4*c+2]=k2*vb.z; xB[4*c+3]=k2*vb.w;
        }
    }
    const float shA = -norms[(size_t)a * T + icA];
    const float shB = -norms[(size_t)a * T + icB];

    float sA = 0.f, sB = 0.f;
    float accA[D], accB[D];
    #pragma unroll
    for (int d = 0; d < D; ++d) { accA[d] = 0.f; accB[d] = 0.f; }

    __shared__ float lt[TR * D];
    __shared__ float lsq[TR];

    for (int t0 = j0; t0 < j1; t0 += TR) {
        const int n = min(TR, j1 - t0);
        __syncthreads();
        {
            const int row = tid >> 1, half = tid & 1;
            if (row < n) {
                const float* r = ybase + (size_t)(t0 + row) * D + half * 16;
                float4 v0 = *(const float4*)(r + 0);
                float4 v1 = *(const float4*)(r + 4);
                float4 v2 = *(const float4*)(r + 8);
                float4 v3 = *(const float4*)(r + 12);
                float* w = &lt[row * D + half * 16];
                *(float4*)(w + 0) = v0; *(float4*)(w + 4) = v1;
                *(float4*)(w + 8) = v2; *(float4*)(w + 12) = v3;
            }
            if (tid < n) lsq[tid] = ny[t0 + tid];
        }
        __syncthreads();
        for (int jj = 0; jj < n; ++jj) {
            const float* yr = &lt[jj * D];            // wave-uniform broadcast
            float yv[D];
            #pragma unroll
            for (int c = 0; c < 8; ++c) *(float4*)&yv[4*c] = *(const float4*)(yr + 4*c);
            const float nyj = lsq[jj];
            float a0 = shA - nyj, a1 = 0.f, a2 = 0.f, a3 = 0.f;
            float b0 = shB - nyj, b1 = 0.f, b2 = 0.f, b3 = 0.f;
            #pragma unroll
            for (int d = 0; d < D; d += 4) {
                a0 = fmaf(xA[d+0], yv[d+0], a0); a1 = fmaf(xA[d+1], yv[d+1], a1);
                a2 = fmaf(xA[d+2], yv[d+2], a2); a3 = fmaf(xA[d+3], yv[d+3], a3);
                b0 = fmaf(xB[d+0], yv[d+0], b0); b1 = fmaf(xB[d+1], yv[d+1], b1);
                b2 = fmaf(xB[d+2], yv[d+2], b2); b3 = fmaf(xB[d+3], yv[d+3], b3);
            }
            const float eA = exp2f((a0 + a1) + (a2 + a3));
            const float eB = exp2f((b0 + b1) + (b2 + b3));
            sA += eA; sB += eB;
            #pragma unroll
            for (int d = 0; d < D; ++d) {
                accA[d] = fmaf(eA, yv[d], accA[d]);
                accB[d] = fmaf(eB, yv[d], accB[d]);
            }
        }
    }

    float* slot = ws1 + (size_t)(dir * JS + js) * 33 * T;
    if (iA < T) {
        slot[iA] = sA;
        #pragma unroll
        for (int d = 0; d < D; ++d) slot[(size_t)(1 + d) * T + iA] = accA[d];
    }
    if (iB < T) {
        slot[iB] = sB;
        #pragma unroll
        for (int d = 0; d < D; ++d) slot[(size_t)(1 + d) * T + iB] = accB[d];
    }
}

// ---------------- K1.5: merge -> ws3 row-major [dir][i][36]: 0..31 = 2L*snn, 32 = -L*|snn|^2 ----------------
__global__ __launch_bounds__(NT)
void ccl_merge_snn(const float* __restrict__ ws1, const int* __restrict__ src_len,
                   const void* __restrict__ comb, float* __restrict__ ws3,
                   int T, int B, int C, int JS, int JC) {
    const int dir = blockIdx.x, pair = dir >> 1, flip = dir & 1;
    int a, b; decode_pair(comb, B, C, pair, flip, a, b);
    const int Lx = src_len[a] >> 2, Ly = src_len[b] >> 2;
    const int r0 = blockIdx.y * NT;
    if (r0 >= Lx) return;
    const int i = r0 + threadIdx.x;
    if (i >= T) return;
    const int nch = min(JS, (Ly + JC - 1) / JC);

    float S = 0.f;
    float sn[D];
    #pragma unroll
    for (int d = 0; d < D; ++d) sn[d] = 0.f;
    for (int ch = 0; ch < nch; ++ch) {
        const float* slot = ws1 + (size_t)(dir * JS + ch) * 33 * T;
        S += slot[i];
        #pragma unroll
        for (int d = 0; d < D; ++d) sn[d] += slot[(size_t)(1 + d) * T + i];
    }
    const float inv = 1.f / S;
    float m2 = 0.f;
    #pragma unroll
    for (int d = 0; d < D; ++d) { sn[d] *= inv; m2 = fmaf(sn[d], sn[d], m2); }
    float* o = ws3 + ((size_t)dir * T + i) * 36;
    const float k2 = 2.f * LOG2E;
    #pragma unroll
    for (int d = 0; d < D; ++d) o[d] = k2 * sn[d];
    o[D] = -LOG2E * m2;
}

// ---------------- K2: phase-B partial, LDS tiles + R=2 rows/lane, fp32 chunk-centered moments ----------------
// ws2 slot (3 float fields): f=0: s, f=1: s1, f=2: s2  (centered at chunk mid)
__global__ __launch_bounds__(NT)
void ccl_phaseB(const float* __restrict__ seq, const int* __restrict__ src_len,
                const void* __restrict__ comb, const float* __restrict__ norms,
                const float* __restrict__ ws3, float* __restrict__ ws2,
                int T, int B, int C, int KS, int KC) {
    const int dir = blockIdx.x, pair = dir >> 1, flip = dir & 1;
    int a, b; decode_pair(comb, B, C, pair, flip, a, b);
    const int Lx = src_len[a] >> 2;
    const int r0 = blockIdx.y * (2 * NT);
    if (r0 >= Lx) return;
    const int ks = blockIdx.z;
    const int k0 = ks * KC;
    if (k0 >= Lx) return;
    const int k1 = min(Lx, k0 + KC);
    const int tid = threadIdx.x;
    const int iA = r0 + tid;
    const int iB = iA + NT;
    const int icA = min(iA, T - 1);
    const int icB = min(iB, T - 1);
    const int kmid = k0 + (KC >> 1);

    const float* __restrict__ xbase = seq + (size_t)a * T * D;
    const float* __restrict__ nx = norms + (size_t)a * T;

    float snA[D], snB[D];
    float shAv, shBv;
    {
        const float* pa = ws3 + ((size_t)dir * T + icA) * 36;
        const float* pb = ws3 + ((size_t)dir * T + icB) * 36;
        #pragma unroll
        for (int c = 0; c < 8; ++c) {
            *(float4*)&snA[4*c] = *(const float4*)(pa + 4*c);
            *(float4*)&snB[4*c] = *(const float4*)(pb + 4*c);
        }
        shAv = pa[D];
        shBv = pb[D];
    }

    float sAq = 0.f, s1A = 0.f, s2A = 0.f;
    float sBq = 0.f, s1B = 0.f, s2B = 0.f;

    __shared__ float lt[TR * D];
    __shared__ float lsq[TR];

    for (int t0 = k0; t0 < k1; t0 += TR) {
        const int n = min(TR, k1 - t0);
        __syncthreads();
        {
            const int row = tid >> 1, half = tid & 1;
            if (row < n) {
                const float* r = xbase + (size_t)(t0 + row) * D + half * 16;
                float4 v0 = *(const float4*)(r + 0);
                float4 v1 = *(const float4*)(r + 4);
                float4 v2 = *(const float4*)(r + 8);
                float4 v3 = *(const float4*)(r + 12);
                float* w = &lt[row * D + half * 16];
                *(float4*)(w + 0) = v0; *(float4*)(w + 4) = v1;
                *(float4*)(w + 8) = v2; *(float4*)(w + 12) = v3;
            }
            if (tid < n) lsq[tid] = nx[t0 + tid];
        }
        __syncthreads();
        for (int kk = 0; kk < n; ++kk) {
            const float* xr = &lt[kk * D];            // wave-uniform broadcast
            float xv[D];
            #pragma unroll
            for (int c = 0; c < 8; ++c) *(float4*)&xv[4*c] = *(const float4*)(xr + 4*c);
            const float nk = lsq[kk];
            float a0 = shAv - nk, a1 = 0.f, a2 = 0.f, a3 = 0.f;
            float b0 = shBv - nk, b1 = 0.f, b2 = 0.f, b3 = 0.f;
            #pragma unroll
            for (int d = 0; d < D; d += 4) {
                a0 = fmaf(snA[d+0], xv[d+0], a0); a1 = fmaf(snA[d+1], xv[d+1], a1);
                a2 = fmaf(snA[d+2], xv[d+2], a2); a3 = fmaf(snA[d+3], xv[d+3], a3);
                b0 = fmaf(snB[d+0], xv[d+0], b0); b1 = fmaf(snB[d+1], xv[d+1], b1);
                b2 = fmaf(snB[d+2], xv[d+2], b2); b3 = fmaf(snB[d+3], xv[d+3], b3);
            }
            const float eA = exp2f((a0 + a1) + (a2 + a3));
            const float eB = exp2f((b0 + b1) + (b2 + b3));
            const float kc = (float)(t0 + kk - kmid);
            sAq += eA; sBq += eB;
            s1A = fmaf(eA, kc, s1A); s1B = fmaf(eB, kc, s1B);
            s2A = fmaf(eA * kc, kc, s2A); s2B = fmaf(eB * kc, kc, s2B);
        }
    }

    float* slot = ws2 + (size_t)(dir * KS + ks) * 3 * T;
    if (iA < T) {
        slot[iA] = sAq;
        slot[(size_t)T + iA] = s1A;
        slot[(size_t)2 * T + iA] = s2A;
    }
    if (iB < T) {
        slot[iB] = sBq;
        slot[(size_t)T + iB] = s1B;
        slot[(size_t)2 * T + iB] = s2B;
    }
}

// ---------------- K3: merge phase-B partials (fp64 shift-to-i) -> li -> sum ----------------
__global__ __launch_bounds__(NT)
void ccl_final(const float* __restrict__ ws2, const int* __restrict__ src_len,
               const void* __restrict__ comb, float* __restrict__ out,
               int T, int B, int C, int KS, int KC) {
    const int dir = blockIdx.x, pair = dir >> 1, flip = dir & 1;
    int a, b; decode_pair(comb, B, C, pair, flip, a, b);
    const int Lx = src_len[a] >> 2;
    const int r0 = blockIdx.y * NT;
    if (r0 >= Lx) return;
    const int tid = threadIdx.x;
    const int i = r0 + tid;
    const int nch = min(KS, (Lx + KC - 1) / KC);

    float li = 0.f;
    if (i < Lx) {
        double S = 0.0, S1 = 0.0, S2 = 0.0;      // centered at i
        for (int ch = 0; ch < nch; ++ch) {
            const float* slot = ws2 + (size_t)(dir * KS + ch) * 3 * T;
            const double sc  = (double)slot[i];
            const double s1c = (double)slot[(size_t)T + i];
            const double s2c = (double)slot[(size_t)2 * T + i];
            const double dc = (double)(ch * KC + (KC >> 1) - i);   // kmid_c - i
            S  += sc;
            S1 += s1c + dc * sc;
            S2 += s2c + dc * (2.0 * s1c + dc * sc);
        }
        const double inv = 1.0 / S;
        const double du = S1 * inv;                    // u - i
        const double var = fma(-du, du, S2 * inv);
        li = (float)(du * du / var) + 0.005f * __logf((float)var);
    }

    float wsum = li;
    #pragma unroll
    for (int off = 32; off > 0; off >>= 1) wsum += __shfl_down(wsum, off, 64);
    __shared__ float red[NT / 64];
    if ((tid & 63) == 0) red[tid >> 6] = wsum;
    __syncthreads();
    if (tid == 0) {
        float t = 0.f;
        #pragma unroll
        for (int w = 0; w < NT / 64; ++w) t += red[w];
        atomicAdd(out, t / (float)C);
    }
}

// ---------------- Fallback: monolithic (known correct) ----------------
__global__ void ccl_mono(const float* __restrict__ seq, const int* __restrict__ src_len,
                         const void* __restrict__ comb, float* __restrict__ out,
                         int T, int B, int C) {
    const int dir = blockIdx.x, pair = dir >> 1, flip = dir & 1;
    int a, b; decode_pair(comb, B, C, pair, flip, a, b);
    const int Lx = src_len[a] >> 2, Ly = src_len[b] >> 2;
    if (blockIdx.y * 64 >= Lx) return;
    const int tid = threadIdx.x;
    const int i = blockIdx.y * 64 + tid;
    const bool valid = (i < Lx);
    const float* __restrict__ xbase = seq + (size_t)a * T * D;
    const float* __restrict__ ybase = seq + (size_t)b * T * D;
    float x[D];
    {
        const float* xr = xbase + (size_t)(valid ? i : (Lx - 1)) * D;
        #pragma unroll
        for (int c = 0; c < 8; ++c) {
            float4 v = *(const float4*)(xr + 4 * c);
            x[4*c] = 2.f*v.x; x[4*c+1] = 2.f*v.y; x[4*c+2] = 2.f*v.z; x[4*c+3] = 2.f*v.w;
        }
    }
    float m = -3.4e38f, s = 0.f;
    float acc[D];
    #pragma unroll
    for (int d = 0; d < D; ++d) acc[d] = 0.f;
    for (int j = 0; j < Ly; ++j) {
        const float* yr = ybase + (size_t)j * D;
        float yv[D]; float q2 = 0.f;
        #pragma unroll
        for (int d = 0; d < D; ++d) { yv[d] = yr[d]; q2 = fmaf(yv[d], yv[d], q2); }
        float d0 = -q2, d1 = 0.f, d2 = 0.f, d3 = 0.f;
        #pragma unroll
        for (int d = 0; d < D; d += 4) {
            d0 = fmaf(x[d], yv[d], d0); d1 = fmaf(x[d+1], yv[d+1], d1);
            d2 = fmaf(x[d+2], yv[d+2], d2); d3 = fmaf(x[d+3], yv[d+3], d3);
        }
        const float sc = (d0 + d1) + (d2 + d3);
        if (__any(sc > m + 8.f)) {
            const float mn = fmaxf(m, sc);
            const float scale = __expf(m - mn);
            const float e = __expf(sc - mn);
            s = fmaf(s, scale, e);
            #pragma unroll
            for (int d = 0; d < D; ++d) acc[d] = fmaf(acc[d], scale, e * yv[d]);
            m = mn;
        } else {
            const float e = __expf(sc - m);
            s += e;
            #pragma unroll
            for (int d = 0; d < D; ++d) acc[d] = fmaf(e, yv[d], acc[d]);
        }
    }
    { const float inv_s = 2.f / s;
      #pragma unroll
      for (int d = 0; d < D; ++d) acc[d] *= inv_s; }
    float mb = -3.4e38f;
    double sb = 0.0, s1 = 0.0, s2m = 0.0;
    const float fi = (float)i;
    for (int k = 0; k < Lx; ++k) {
        const float* xr = xbase + (size_t)k * D;
        float xv[D]; float q2 = 0.f;
        #pragma unroll
        for (int d = 0; d < D; ++d) { xv[d] = xr[d]; q2 = fmaf(xv[d], xv[d], q2); }
        float d0 = -q2, d1 = 0.f, d2 = 0.f, d3 = 0.f;
        #pragma unroll
        for (int d = 0; d < D; d += 4) {
            d0 = fmaf(acc[d], xv[d], d0); d1 = fmaf(acc[d+1], xv[d+1], d1);
            d2 = fmaf(acc[d+2], xv[d+2], d2); d3 = fmaf(acc[d+3], xv[d+3], d3);
        }
        const float sc = (d0 + d1) + (d2 + d3);
        const float kc = (float)k - fi;
        if (__any(sc > mb + 8.f)) {
            const float mn = fmaxf(mb, sc);
            const double scale = (double)__expf(mb - mn);
            const double e = (double)__expf(sc - mn);
            sb = sb * scale + e; s1 = s1 * scale + e * kc; s2m = s2m * scale + e * kc * kc;
            mb = mn;
        } else {
            const double e = (double)__expf(sc - mb);
            sb += e; s1 = fma(e, (double)kc, s1); s2m = fma(e * kc, (double)kc, s2m);
        }
    }
    float li = 0.f;
    if (valid) {
        const double inv = 1.0 / sb;
        const double du = s1 * inv;
        const double var = fma(-du, du, s2m * inv);
        li = (float)(du * du / var) + 0.005f * __logf((float)var);
    }
    float wsum = li;
    #pragma unroll
    for (int off = 32; off > 0; off >>= 1) wsum += __shfl_down(wsum, off, 64);
    if (tid == 0) atomicAdd(out, wsum * (1.0f / (float)C));
}

extern "C" void kernel_launch(void* const* d_in, const int* in_sizes, int n_in,
                              void* d_out, int out_size, void* d_ws, size_t ws_size,
                              hipStream_t stream) {
    const float* seq = (const float*)d_in[0];
    const int* src_len = (const int*)d_in[1];
    const void* comb = (const void*)d_in[2];
    float* out = (float*)d_out;

    const int B = in_sizes[1];
    const int C = in_sizes[2] / 2;
    const int T = in_sizes[0] / (B * D);
    const int RT = (T + NT - 1) / NT;              // merge/final row blocks
    const int RT2 = (T + 2 * NT - 1) / (2 * NT);   // phase kernels (R=2 rows/lane)
    const int nrows = B * T;

    auto need = [&](int js, int ks) -> size_t {
        return 4 * ((size_t)nrows
                    + (size_t)2 * C * js * 33 * T     // ws1
                    + (size_t)2 * C * T * 36          // ws3
                    + (size_t)2 * C * ks * 3 * T);    // ws2
    };
    int JS = 16, KS = 32;
    while (JS > 1 && need(JS, KS) > ws_size) { JS >>= 1; KS >>= 1; }

    hipMemsetAsync(out, 0, sizeof(float), stream);

    if (need(JS, KS) <= ws_size) {
        const int JC = (T + JS - 1) / JS;
        const int KC = (T + KS - 1) / KS;
        float* norms = (float*)d_ws;
        float* ws1 = norms + nrows;
        float* ws3 = ws1 + (size_t)2 * C * JS * 33 * T;
        float* ws2 = ws3 + (size_t)2 * C * T * 36;
        row_norms<<<(nrows + 255) / 256, 256, 0, stream>>>(seq, norms, nrows);
        ccl_phaseA<<<dim3(2 * C, RT2, JS), NT, 0, stream>>>(seq, src_len, comb, norms, ws1, T, B, C, JS, JC);
        ccl_merge_snn<<<dim3(2 * C, RT), NT, 0, stream>>>(ws1, src_len, comb, ws3, T, B, C, JS, JC);
        ccl_phaseB<<<dim3(2 * C, RT2, KS), NT, 0, stream>>>(seq, src_len, comb, norms, ws3, ws2, T, B, C, KS, KC);
        ccl_final<<<dim3(2 * C, RT), NT, 0, stream>>>(ws2, src_len, comb, out, T, B, C, KS, KC);
    } else {
        dim3 grid(2 * C, (T + 63) / 64);
        ccl_mono<<<grid, 64, 0, stream>>>(seq, src_len, comb, out, T, B, C);
    }
}

// Round 10
// 309.412 us; speedup vs baseline: 2.1085x; 2.1085x over previous
//
#include <hip/hip_runtime.h>

#define D 32
#define LOG2E 1.4426950408889634f
#define TWOL  (2.0f * 1.4426950408889634f)

typedef __attribute__((ext_vector_type(8))) short short8v;
typedef __attribute__((ext_vector_type(4))) short short4v;
typedef __attribute__((ext_vector_type(4))) float f32x4;
typedef unsigned short ushortv;

static __device__ __forceinline__ unsigned cvt_pk_bf16(float a, float b) {
    unsigned r;
    asm volatile("v_cvt_pk_bf16_f32 %0, %1, %2" : "=v"(r) : "v"(a), "v"(b));
    return r;
}

static __device__ __forceinline__ f32x4 mfma32(short8v a, short8v b, f32x4 c) {
    return __builtin_amdgcn_mfma_f32_16x16x32_bf16(a, b, c, 0, 0, 0);
}

#if __has_builtin(__builtin_amdgcn_mfma_f32_16x16x16bf16_1k)
static __device__ __forceinline__ f32x4 mfma16(short4v a, short4v b, f32x4 c) {
    return __builtin_amdgcn_mfma_f32_16x16x16bf16_1k(a, b, c, 0, 0, 0);
}
#else
static __device__ __forceinline__ f32x4 mfma16(short4v a, short4v b, f32x4 c) {
    asm volatile("s_nop 1\n\tv_mfma_f32_16x16x16_bf16 %0, %1, %2, %0"
                 : "+v"(c) : "v"(a), "v"(b));
    return c;
}
#endif

static __device__ __forceinline__ unsigned short f2bf(float f) {   // RNE f32->bf16
    unsigned u = __float_as_uint(f);
    u += 0x7FFFu + ((u >> 16) & 1u);
    return (unsigned short)(u >> 16);
}
static __device__ __forceinline__ float bf2f(unsigned short h) {
    return __uint_as_float((unsigned)h << 16);
}

__device__ __forceinline__ void decode_pair(const void* comb, int B, int C,
                                            int pair, int flip, int& a, int& b) {
    const long long* c64 = (const long long*)comb;
    const int* c32 = (const int*)comb;
    bool is64 = true;
    for (int q = 0; q < C; ++q) {
        long long v = c64[q];
        if (v < 0 || v >= (long long)B) { is64 = false; break; }
    }
    if (is64) { a = (int)c64[2 * pair]; b = (int)c64[2 * pair + 1]; }
    else      { a = c32[2 * pair];      b = c32[2 * pair + 1]; }
    if (flip) { int t = a; a = b; b = t; }
}

// ---------------- prep: fp32 seq -> bf16 row-major xb[b][r][d] + transposed ybT[b][d][r], zero-padded rows ----------------
__global__ __launch_bounds__(256)
void prep(const float* __restrict__ seq, unsigned short* __restrict__ xb,
          unsigned short* __restrict__ ybT, int T, int TP, int B) {
    const int b = blockIdx.x;
    const int r = blockIdx.y * 64 + (threadIdx.x >> 2);
    const int c0 = (threadIdx.x & 3) * 8;
    if (r >= TP) return;
    unsigned short h[8];
    if (r < T) {
        const float* p = seq + ((size_t)b * T + r) * D + c0;
        float4 v0 = *(const float4*)p;
        float4 v1 = *(const float4*)(p + 4);
        h[0]=f2bf(v0.x); h[1]=f2bf(v0.y); h[2]=f2bf(v0.z); h[3]=f2bf(v0.w);
        h[4]=f2bf(v1.x); h[5]=f2bf(v1.y); h[6]=f2bf(v1.z); h[7]=f2bf(v1.w);
    } else {
        #pragma unroll
        for (int e = 0; e < 8; ++e) h[e] = 0;
    }
    unsigned out[4];
    out[0] = (unsigned)h[0] | ((unsigned)h[1] << 16);
    out[1] = (unsigned)h[2] | ((unsigned)h[3] << 16);
    out[2] = (unsigned)h[4] | ((unsigned)h[5] << 16);
    out[3] = (unsigned)h[6] | ((unsigned)h[7] << 16);
    *(uint4*)(xb + ((size_t)b * TP + r) * D + c0) = make_uint4(out[0], out[1], out[2], out[3]);
    #pragma unroll
    for (int e = 0; e < 8; ++e)
        ybT[((size_t)b * D + c0 + e) * TP + r] = h[e];
}

// ---------------- lnorms: lnm[b][r] = log2(e) * |row_bf16|^2 (pad rows -> 0) ----------------
__global__ __launch_bounds__(256)
void lnorms(const unsigned short* __restrict__ xb, float* __restrict__ lnm, int n) {
    const int r = blockIdx.x * 256 + threadIdx.x;
    if (r >= n) return;
    const unsigned short* p = xb + (size_t)r * D;
    float s = 0.f;
    #pragma unroll
    for (int d = 0; d < D; ++d) { float f = bf2f(p[d]); s = fmaf(f, f, s); }
    lnm[r] = LOG2E * s;
}

// ---------------- phase A (MFMA): partial softmin + weighted sum over a j-chunk ----------------
// ws1 layout: [dir*JS+js][TP rows][36]: fields 0..31 = acc[d], 32 = s
__global__ __launch_bounds__(256)
void mfmaA(const unsigned short* __restrict__ xball, const unsigned short* __restrict__ ybTall,
           const float* __restrict__ lnmall, const int* __restrict__ src_len,
           const void* __restrict__ comb, float* __restrict__ ws1,
           int T, int TP, int B, int C, int JS, int JC) {
    const int dir = blockIdx.x, pair = dir >> 1, flip = dir & 1;
    int a, b; decode_pair(comb, B, C, pair, flip, a, b);
    const int Lx = src_len[a] >> 2, Ly = src_len[b] >> 2;
    const int r0 = blockIdx.y * 64;
    if (r0 >= Lx) return;
    const int js = blockIdx.z;
    const int j0 = js * JC;
    if (j0 >= Ly) return;
    const int j1 = min(Ly, j0 + JC);

    const int tid = threadIdx.x;
    const int l = tid & 63, w = tid >> 6;
    const int lr = l & 15, lg = l >> 4;
    const int q0 = r0 + w * 16;

    const unsigned short* xb = xball + (size_t)a * TP * D;
    const unsigned short* yb = xball + (size_t)b * TP * D;
    const unsigned short* ybT0 = ybTall + (size_t)b * TP * D + (size_t)lr * TP;
    const unsigned short* ybT1 = ybT0 + (size_t)16 * TP;
    const float* lny = lnmall + (size_t)b * TP;

    // Q B-frag: B[k=d][col=q]: lane reads x row (q0+lr), d = 8*lg..+8
    short8v qf = *(const short8v*)(xb + (size_t)(q0 + lr) * D + lg * 8);
    const float lnq = lnmall[(size_t)a * TP + q0 + lr];

    f32x4 acc0 = {0.f, 0.f, 0.f, 0.f};
    f32x4 acc1 = {0.f, 0.f, 0.f, 0.f};
    float srow = 0.f;
    const f32x4 zero4 = {0.f, 0.f, 0.f, 0.f};

    for (int kk = j0; kk < j1; kk += 16) {
        // K A-frag: A[row=key][k=d]
        short8v kf = *(const short8v*)(yb + (size_t)(kk + lr) * D + lg * 8);
        float4 ln4 = *(const float4*)(lny + kk + 4 * lg);
        f32x4 c1 = mfma32(kf, qf, zero4);        // C1[key=4lg+r][q=lr]
        float e0 = exp2f(fmaf(TWOL, c1[0], -(lnq + ln4.x)));
        float e1 = exp2f(fmaf(TWOL, c1[1], -(lnq + ln4.y)));
        float e2 = exp2f(fmaf(TWOL, c1[2], -(lnq + ln4.z)));
        float e3 = exp2f(fmaf(TWOL, c1[3], -(lnq + ln4.w)));
        if (kk + 16 > Ly) {                      // tail: hard-mask padded keys
            const int kb = kk + 4 * lg;
            e0 = (kb + 0 < Ly) ? e0 : 0.f;
            e1 = (kb + 1 < Ly) ? e1 : 0.f;
            e2 = (kb + 2 < Ly) ? e2 : 0.f;
            e3 = (kb + 3 < Ly) ? e3 : 0.f;
        }
        srow += (e0 + e1) + (e2 + e3);
        union { unsigned u[2]; short4v s; } cv;
        cv.u[0] = cvt_pk_bf16(e0, e1);
        cv.u[1] = cvt_pk_bf16(e2, e3);
        const short4v af = cv.s;                 // A[q=lr][key=4lg+r]  (C1 layout == A16 layout)
        const short4v b0 = *(const short4v*)(ybT0 + kk + 4 * lg);   // B[key][d=lr]
        const short4v b1 = *(const short4v*)(ybT1 + kk + 4 * lg);   // B[key][d=lr+16]
        acc0 = mfma16(af, b0, acc0);             // C2[q=4lg+r][d=lr]
        acc1 = mfma16(af, b1, acc1);
    }
    asm volatile("s_nop 7\n\ts_nop 7" ::: "memory");

    srow += __shfl_xor(srow, 16);
    srow += __shfl_xor(srow, 32);

    float* slot = ws1 + (size_t)(dir * JS + js) * TP * 36;
    #pragma unroll
    for (int r = 0; r < 4; ++r) {
        const int q = q0 + 4 * lg + r;
        slot[(size_t)q * 36 + lr] = acc0[r];
        slot[(size_t)q * 36 + lr + 16] = acc1[r];
    }
    if (l < 16) slot[(size_t)(q0 + l) * 36 + 32] = srow;
}

// ---------------- merge: sum chunk partials -> snn bf16 rows + lnq ----------------
__global__ __launch_bounds__(256)
void merge_snn(const float* __restrict__ ws1, const int* __restrict__ src_len,
               const void* __restrict__ comb, unsigned short* __restrict__ ws3h,
               float* __restrict__ ws3n, int T, int TP, int B, int C, int JS, int JC) {
    const int dir = blockIdx.x, pair = dir >> 1, flip = dir & 1;
    int a, b; decode_pair(comb, B, C, pair, flip, a, b);
    const int Lx = src_len[a] >> 2, Ly = src_len[b] >> 2;
    const int r0 = blockIdx.y * 256;
    if (r0 >= Lx) return;
    const int i = r0 + threadIdx.x;
    if (i >= T) return;
    const int nch = min(JS, (Ly + JC - 1) / JC);

    float S = 0.f;
    float sn[D];
    #pragma unroll
    for (int d = 0; d < D; ++d) sn[d] = 0.f;
    for (int ch = 0; ch < nch; ++ch) {
        const float* slot = ws1 + ((size_t)(dir * JS + ch) * TP + i) * 36;
        S += slot[32];
        #pragma unroll
        for (int d = 0; d < D; ++d) sn[d] += slot[d];
    }
    const float inv = (S > 0.f) ? 1.f / S : 0.f;
    unsigned short* o = ws3h + ((size_t)dir * TP + i) * D;
    float m2 = 0.f;
    #pragma unroll
    for (int d = 0; d < D; ++d) {
        const unsigned short hh = f2bf(sn[d] * inv);
        o[d] = hh;
        const float vb = bf2f(hh);
        m2 = fmaf(vb, vb, m2);
    }
    ws3n[(size_t)dir * TP + i] = LOG2E * m2;
}

// ---------------- phase B (MFMA): chunk-centered fp32 moments ----------------
// ws2 layout: [dir*KS+ks][3 fields x TP]: s, s1, s2 (centered at kmid)
__global__ __launch_bounds__(256)
void mfmaB(const unsigned short* __restrict__ xball, const unsigned short* __restrict__ ws3h,
           const float* __restrict__ ws3n, const float* __restrict__ lnmall,
           const int* __restrict__ src_len, const void* __restrict__ comb,
           float* __restrict__ ws2, int T, int TP, int B, int C, int KS, int KC) {
    const int dir = blockIdx.x, pair = dir >> 1, flip = dir & 1;
    int a, b; decode_pair(comb, B, C, pair, flip, a, b);
    const int Lx = src_len[a] >> 2;
    const int r0 = blockIdx.y * 64;
    if (r0 >= Lx) return;
    const int ks = blockIdx.z;
    const int k0 = ks * KC;
    if (k0 >= Lx) return;
    const int k1 = min(Lx, k0 + KC);
    const int kmid = k0 + (KC >> 1);

    const int tid = threadIdx.x;
    const int l = tid & 63, w = tid >> 6;
    const int lr = l & 15, lg = l >> 4;
    const int q0 = r0 + w * 16;

    const unsigned short* xb = xball + (size_t)a * TP * D;
    const float* lnx = lnmall + (size_t)a * TP;

    short8v qf = *(const short8v*)(ws3h + ((size_t)dir * TP + q0 + lr) * D + lg * 8);
    const float lnq = ws3n[(size_t)dir * TP + q0 + lr];

    float s = 0.f, s1 = 0.f, s2 = 0.f;
    const f32x4 zero4 = {0.f, 0.f, 0.f, 0.f};

    for (int kk = k0; kk < k1; kk += 16) {
        short8v kf = *(const short8v*)(xb + (size_t)(kk + lr) * D + lg * 8);
        float4 ln4 = *(const float4*)(lnx + kk + 4 * lg);
        f32x4 c1 = mfma32(kf, qf, zero4);
        float e0 = exp2f(fmaf(TWOL, c1[0], -(lnq + ln4.x)));
        float e1 = exp2f(fmaf(TWOL, c1[1], -(lnq + ln4.y)));
        float e2 = exp2f(fmaf(TWOL, c1[2], -(lnq + ln4.z)));
        float e3 = exp2f(fmaf(TWOL, c1[3], -(lnq + ln4.w)));
        if (kk + 16 > Lx) {
            const int kb = kk + 4 * lg;
            e0 = (kb + 0 < Lx) ? e0 : 0.f;
            e1 = (kb + 1 < Lx) ? e1 : 0.f;
            e2 = (kb + 2 < Lx) ? e2 : 0.f;
            e3 = (kb + 3 < Lx) ? e3 : 0.f;
        }
        const float kb = (float)(kk + 4 * lg - kmid);
        s += (e0 + e1) + (e2 + e3);
        s1 = fmaf(e0, kb, s1);          s2 = fmaf(e0 * kb, kb, s2);
        const float k1f = kb + 1.f;
        s1 = fmaf(e1, k1f, s1);         s2 = fmaf(e1 * k1f, k1f, s2);
        const float k2f = kb + 2.f;
        s1 = fmaf(e2, k2f, s1);         s2 = fmaf(e2 * k2f, k2f, s2);
        const float k3f = kb + 3.f;
        s1 = fmaf(e3, k3f, s1);         s2 = fmaf(e3 * k3f, k3f, s2);
    }

    s  += __shfl_xor(s, 16);  s  += __shfl_xor(s, 32);
    s1 += __shfl_xor(s1, 16); s1 += __shfl_xor(s1, 32);
    s2 += __shfl_xor(s2, 16); s2 += __shfl_xor(s2, 32);

    if (l < 16) {
        float* slot = ws2 + (size_t)(dir * KS + ks) * 3 * TP;
        const int i = q0 + l;
        slot[i] = s;
        slot[(size_t)TP + i] = s1;
        slot[(size_t)2 * TP + i] = s2;
    }
}

// ---------------- final: merge chunk moments (fp64 shift-to-i) -> li -> sum ----------------
__global__ __launch_bounds__(256)
void ccl_final(const float* __restrict__ ws2, const int* __restrict__ src_len,
               const void* __restrict__ comb, float* __restrict__ out,
               int T, int TP, int B, int C, int KS, int KC) {
    const int dir = blockIdx.x, pair = dir >> 1, flip = dir & 1;
    int a, b; decode_pair(comb, B, C, pair, flip, a, b);
    const int Lx = src_len[a] >> 2;
    const int r0 = blockIdx.y * 256;
    if (r0 >= Lx) return;
    const int tid = threadIdx.x;
    const int i = r0 + tid;
    const int nch = min(KS, (Lx + KC - 1) / KC);

    float li = 0.f;
    if (i < Lx) {
        double S = 0.0, S1 = 0.0, S2 = 0.0;
        for (int ch = 0; ch < nch; ++ch) {
            const float* slot = ws2 + (size_t)(dir * KS + ch) * 3 * TP;
            const double sc  = (double)slot[i];
            const double s1c = (double)slot[(size_t)TP + i];
            const double s2c = (double)slot[(size_t)2 * TP + i];
            const double dc = (double)(ch * KC + (KC >> 1) - i);
            S  += sc;
            S1 += s1c + dc * sc;
            S2 += s2c + dc * (2.0 * s1c + dc * sc);
        }
        const double inv = 1.0 / S;
        const double du = S1 * inv;
        const double var = fma(-du, du, S2 * inv);
        li = (float)(du * du / var) + 0.005f * __logf((float)var);
    }

    float wsum = li;
    #pragma unroll
    for (int off = 32; off > 0; off >>= 1) wsum += __shfl_down(wsum, off, 64);
    __shared__ float red[4];
    if ((tid & 63) == 0) red[tid >> 6] = wsum;
    __syncthreads();
    if (tid == 0) atomicAdd(out, (red[0] + red[1] + red[2] + red[3]) / (float)C);
}

// ---------------- Fallback: monolithic fp32 (validated lineage) ----------------
__global__ void ccl_mono(const float* __restrict__ seq, const int* __restrict__ src_len,
                         const void* __restrict__ comb, float* __restrict__ out,
                         int T, int B, int C) {
    const int dir = blockIdx.x, pair = dir >> 1, flip = dir & 1;
    int a, b; decode_pair(comb, B, C, pair, flip, a, b);
    const int Lx = src_len[a] >> 2, Ly = src_len[b] >> 2;
    if (blockIdx.y * 64 >= Lx) return;
    const int tid = threadIdx.x;
    const int i = blockIdx.y * 64 + tid;
    const bool valid = (i < Lx);
    const float* __restrict__ xbase = seq + (size_t)a * T * D;
    const float* __restrict__ ybase = seq + (size_t)b * T * D;
    float x[D];
    {
        const float* xr = xbase + (size_t)(valid ? i : (Lx - 1)) * D;
        #pragma unroll
        for (int c = 0; c < 8; ++c) {
            float4 v = *(const float4*)(xr + 4 * c);
            x[4*c] = 2.f*v.x; x[4*c+1] = 2.f*v.y; x[4*c+2] = 2.f*v.z; x[4*c+3] = 2.f*v.w;
        }
    }
    float m = -3.4e38f, s = 0.f;
    float acc[D];
    #pragma unroll
    for (int d = 0; d < D; ++d) acc[d] = 0.f;
    for (int j = 0; j < Ly; ++j) {
        const float* yr = ybase + (size_t)j * D;
        float yv[D]; float q2 = 0.f;
        #pragma unroll
        for (int d = 0; d < D; ++d) { yv[d] = yr[d]; q2 = fmaf(yv[d], yv[d], q2); }
        float d0 = -q2, d1 = 0.f, d2 = 0.f, d3 = 0.f;
        #pragma unroll
        for (int d = 0; d < D; d += 4) {
            d0 = fmaf(x[d], yv[d], d0); d1 = fmaf(x[d+1], yv[d+1], d1);
            d2 = fmaf(x[d+2], yv[d+2], d2); d3 = fmaf(x[d+3], yv[d+3], d3);
        }
        const float sc = (d0 + d1) + (d2 + d3);
        if (__any(sc > m + 8.f)) {
            const float mn = fmaxf(m, sc);
            const float scale = __expf(m - mn);
            const float e = __expf(sc - mn);
            s = fmaf(s, scale, e);
            #pragma unroll
            for (int d = 0; d < D; ++d) acc[d] = fmaf(acc[d], scale, e * yv[d]);
            m = mn;
        } else {
            const float e = __expf(sc - m);
            s += e;
            #pragma unroll
            for (int d = 0; d < D; ++d) acc[d] = fmaf(e, yv[d], acc[d]);
        }
    }
    { const float inv_s = 2.f / s;
      #pragma unroll
      for (int d = 0; d < D; ++d) acc[d] *= inv_s; }
    float mb = -3.4e38f;
    double sb = 0.0, s1 = 0.0, s2m = 0.0;
    const float fi = (float)i;
    for (int k = 0; k < Lx; ++k) {
        const float* xr = xbase + (size_t)k * D;
        float xv[D]; float q2 = 0.f;
        #pragma unroll
        for (int d = 0; d < D; ++d) { xv[d] = xr[d]; q2 = fmaf(xv[d], xv[d], q2); }
        float d0 = -q2, d1 = 0.f, d2 = 0.f, d3 = 0.f;
        #pragma unroll
        for (int d = 0; d < D; d += 4) {
            d0 = fmaf(acc[d], xv[d], d0); d1 = fmaf(acc[d+1], xv[d+1], d1);
            d2 = fmaf(acc[d+2], xv[d+2], d2); d3 = fmaf(acc[d+3], xv[d+3], d3);
        }
        const float sc = (d0 + d1) + (d2 + d3);
        const float kc = (float)k - fi;
        if (__any(sc > mb + 8.f)) {
            const float mn = fmaxf(mb, sc);
            const double scale = (double)__expf(mb - mn);
            const double e = (double)__expf(sc - mn);
            sb = sb * scale + e; s1 = s1 * scale + e * kc; s2m = s2m * scale + e * kc * kc;
            mb = mn;
        } else {
            const double e = (double)__expf(sc - mb);
            sb += e; s1 = fma(e, (double)kc, s1); s2m = fma(e * kc, (double)kc, s2m);
        }
    }
    float li = 0.f;
    if (valid) {
        const double inv = 1.0 / sb;
        const double du = s1 * inv;
        const double var = fma(-du, du, s2m * inv);
        li = (float)(du * du / var) + 0.005f * __logf((float)var);
    }
    float wsum = li;
    #pragma unroll
    for (int off = 32; off > 0; off >>= 1) wsum += __shfl_down(wsum, off, 64);
    if (tid == 0) atomicAdd(out, wsum * (1.0f / (float)C));
}

extern "C" void kernel_launch(void* const* d_in, const int* in_sizes, int n_in,
                              void* d_out, int out_size, void* d_ws, size_t ws_size,
                              hipStream_t stream) {
    const float* seq = (const float*)d_in[0];
    const int* src_len = (const int*)d_in[1];
    const void* comb = (const void*)d_in[2];
    float* out = (float*)d_out;

    const int B = in_sizes[1];
    const int C = in_sizes[2] / 2;
    const int T = in_sizes[0] / (B * D);
    const int ND = 2 * C;
    const int TP = T + 64;
    const int JS = 4, KS = 8;
    const int JC = (((T + JS - 1) / JS + 15) / 16) * 16;
    const int KC = (((T + KS - 1) / KS + 15) / 16) * 16;

    auto al = [](size_t x) { return (x + 255) & ~(size_t)255; };
    const size_t sz_lnm = al((size_t)B * TP * 4);
    const size_t sz_xb  = al((size_t)B * TP * D * 2);
    const size_t sz_ybT = al((size_t)B * TP * D * 2);
    const size_t sz_ws1 = al((size_t)ND * JS * TP * 36 * 4);
    const size_t sz_w3h = al((size_t)ND * TP * D * 2);
    const size_t sz_w3n = al((size_t)ND * TP * 4);
    const size_t sz_ws2 = al((size_t)ND * KS * 3 * TP * 4);
    const size_t need = sz_lnm + sz_xb + sz_ybT + sz_ws1 + sz_w3h + sz_w3n + sz_ws2;

    hipMemsetAsync(out, 0, sizeof(float), stream);

    if (need <= ws_size) {
        char* p = (char*)d_ws;
        float* lnm = (float*)p;            p += sz_lnm;
        unsigned short* xb = (unsigned short*)p;   p += sz_xb;
        unsigned short* ybT = (unsigned short*)p;  p += sz_ybT;
        float* ws1 = (float*)p;            p += sz_ws1;
        unsigned short* ws3h = (unsigned short*)p; p += sz_w3h;
        float* ws3n = (float*)p;           p += sz_w3n;
        float* ws2 = (float*)p;

        prep<<<dim3(B, (TP + 63) / 64), 256, 0, stream>>>(seq, xb, ybT, T, TP, B);
        lnorms<<<(B * TP + 255) / 256, 256, 0, stream>>>(xb, lnm, B * TP);
        mfmaA<<<dim3(ND, (T + 63) / 64, JS), 256, 0, stream>>>(
            xb, ybT, lnm, src_len, comb, ws1, T, TP, B, C, JS, JC);
        merge_snn<<<dim3(ND, (T + 255) / 256), 256, 0, stream>>>(
            ws1, src_len, comb, ws3h, ws3n, T, TP, B, C, JS, JC);
        mfmaB<<<dim3(ND, (T + 63) / 64, KS), 256, 0, stream>>>(
            xb, ws3h, ws3n, lnm, src_len, comb, ws2, T, TP, B, C, KS, KC);
        ccl_final<<<dim3(ND, (T + 255) / 256), 256, 0, stream>>>(
            ws2, src_len, comb, out, T, TP, B, C, KS, KC);
    } else {
        dim3 grid(ND, (T + 63) / 64);
        ccl_mono<<<grid, 64, 0, stream>>>(seq, src_len, comb, out, T, B, C);
    }
}